// Round 2
// baseline (830.184 us; speedup 1.0000x reference)
//
#include <hip/hip_runtime.h>

// Problem constants
#define NN   768
#define KKN  32
#define CS   384
#define CZ   128
#define CG   16
#define NH   4
#define DHD  32
#define NRBF 64
#define EE   (NN*KKN)

#define RBF_STEP    (20.0f/63.0f)
#define RBF_INVSTEP (63.0f/20.0f)
#define RBF_INVSIG  3.2f            // 1/0.3125

// ---------- helpers ----------
__device__ __forceinline__ unsigned short f2bf(float f){
  unsigned int u = __float_as_uint(f);
  u += 0x7FFFu + ((u >> 16) & 1u);
  return (unsigned short)(u >> 16);
}
__device__ __forceinline__ float bfl(unsigned int u){ return __uint_as_float(u << 16); }
__device__ __forceinline__ float bfh(unsigned int u){ return __uint_as_float(u & 0xFFFF0000u); }
__device__ __forceinline__ unsigned int packbf(float a, float b){
  return (unsigned int)f2bf(a) | ((unsigned int)f2bf(b) << 16);
}
__device__ __forceinline__ float sigm(float x){ return 1.0f/(1.0f + __expf(-x)); }
__device__ __forceinline__ int r0_of(float d){
  int c = (int)floorf(d*RBF_INVSTEP + 0.5f) - 8;
  c = c < 0 ? 0 : c;
  return c > 48 ? 48 : c;
}

// ---------- K1: nl/nr projections + LayerNorm(edge_features) -> bf16 z ----------
__global__ __launch_bounds__(256) void k1_pre(
    const float* __restrict__ nf, const float* __restrict__ ef,
    const float* __restrict__ wl, const float* __restrict__ bl,
    const float* __restrict__ wr, const float* __restrict__ br,
    const float* __restrict__ lng, const float* __restrict__ lnb,
    float* __restrict__ nlw, float* __restrict__ nrw,
    unsigned short* __restrict__ zw)
{
  int b = blockIdx.x, t = threadIdx.x;
  if (b < 1536){
    // LayerNorm: 16 rows/block, 16 lanes/row, 8 channels/lane
    int rl = t >> 4, l16 = t & 15;
    size_t e = (size_t)b*16 + rl;
    const float4* row = (const float4*)(ef + e*CZ);
    float4 x0 = row[l16*2], x1 = row[l16*2+1];
    float v[8] = {x0.x,x0.y,x0.z,x0.w,x1.x,x1.y,x1.z,x1.w};
    float s = 0.f, q = 0.f;
    #pragma unroll
    for (int u=0;u<8;u++){ s += v[u]; q += v[u]*v[u]; }
    #pragma unroll
    for (int m=1;m<16;m<<=1){ s += __shfl_xor(s,m); q += __shfl_xor(q,m); }
    float mean = s*(1.f/128.f);
    float var  = q*(1.f/128.f) - mean*mean;
    float rs = rsqrtf(var + 1e-5f);
    int c0 = l16*8;
    unsigned int pk[4];
    #pragma unroll
    for (int u=0;u<4;u++){
      float z0 = (v[2*u]  -mean)*rs*lng[c0+2*u]   + lnb[c0+2*u];
      float z1 = (v[2*u+1]-mean)*rs*lng[c0+2*u+1] + lnb[c0+2*u+1];
      pk[u] = packbf(z0,z1);
    }
    ((uint4*)(zw + e*CZ))[l16] = make_uint4(pk[0],pk[1],pk[2],pk[3]);
  } else {
    // nl/nr: one output per thread (dot over 384)
    int gid = (b-1536)*256 + t;           // 0..24575
    int side = (gid >= 12288) ? 1 : 0;
    int idx = gid - side*12288;
    int nd = idx >> 4, c = idx & 15;
    const float* w = side ? wr : wl;
    float acc = side ? br[c] : bl[c];
    const float* nrow = nf + (size_t)nd*CS;
    #pragma unroll 4
    for (int k=0;k<CS;k++) acc += nrow[k]*w[k*CG+c];
    (side? nrw : nlw)[idx] = acc;
  }
}

// ---------- K2: bias[n,i,j,h] (gate x rbf x tobias), per (node, 4-i chunk) ----------
__global__ __launch_bounds__(256) void k2_bias(
    const long long* __restrict__ eidx, const float* __restrict__ trans,
    const float* __restrict__ nlw, const float* __restrict__ nrw,
    const float* __restrict__ wb, const float* __restrict__ bg,
    const float* __restrict__ wd, const float* __restrict__ bd,
    const float* __restrict__ wt,
    float* __restrict__ biasw)
{
  int n = blockIdx.x >> 3, chunk = blockIdx.x & 7;
  int i0 = chunk*4;
  int t = threadIdx.x;

  __shared__ __align__(16) float S4[4][16][128];          // 32 KB  S[i_loc][l][c]
  __shared__ __align__(16) unsigned int wdu[64][64];      // 16 KB  w_dist bf16-packed
  __shared__ __align__(16) float rbfs[64][32];            //  8 KB  rbf[r][j] for current i
  __shared__ __align__(16) float e2T[16][32];             //  2 KB
  __shared__ __align__(16) float e1c[4][16];
  __shared__ __align__(16) float t3s[32][4];
  __shared__ __align__(16) float dsm[4][32];
  __shared__ __align__(16) float bgs[128];
  __shared__ __align__(16) float bds[128];
  __shared__ __align__(16) float wts[128][4];
  __shared__ int srcs[32];

  // ph0: sources + stage w_dist (bf16) + small vectors
  if (t < 32) srcs[t] = (int)eidx[(size_t)n*KKN + t];
  #pragma unroll
  for (int q=0;q<16;q++){
    int ui = t + q*256;                                   // 0..4095 uint index
    float2 wp = ((const float2*)wd)[ui];
    wdu[ui>>6][ui&63] = packbf(wp.x, wp.y);
  }
  if (t < 128){
    bgs[t] = bg[t]; bds[t] = bd[t];
    ((float4*)wts)[t] = ((const float4*)wt)[t];
  }
  __syncthreads();

  // ph1: gathers
  if (t < 64){ int ii = t>>4, k = t&15; e1c[ii][k] = nlw[srcs[i0+ii]*CG + k]; }
  { int j = t >> 3, l0 = (t&7)*2;
    float a = nrw[srcs[j]*CG + l0], b2 = nrw[srcs[j]*CG + l0+1];
    e2T[l0][j] = a; e2T[l0+1][j] = b2; }
  if (t < 32){ int s = srcs[t];
    t3s[t][0]=trans[s*3]; t3s[t][1]=trans[s*3+1]; t3s[t][2]=trans[s*3+2]; }
  __syncthreads();

  // ph2: S4 tile (reads w_bgate exactly once per block) + distances
  {
    int l = t >> 4, co = t & 15;
    float sacc[4][8];
    #pragma unroll
    for (int a=0;a<4;a++)
      #pragma unroll
      for (int b2=0;b2<8;b2++) sacc[a][b2]=0.f;
    #pragma unroll
    for (int k=0;k<16;k++){
      const float4* wrow = (const float4*)(wb + (size_t)(k*16+l)*128 + co*8);
      float4 w0 = wrow[0], w1 = wrow[1];
      float e0=e1c[0][k], e1_=e1c[1][k], e2_=e1c[2][k], e3=e1c[3][k];
      float wv[8] = {w0.x,w0.y,w0.z,w0.w,w1.x,w1.y,w1.z,w1.w};
      #pragma unroll
      for (int u=0;u<8;u++){
        sacc[0][u] += e0*wv[u]; sacc[1][u] += e1_*wv[u];
        sacc[2][u] += e2_*wv[u]; sacc[3][u] += e3*wv[u];
      }
    }
    #pragma unroll
    for (int ii=0;ii<4;ii++){
      ((float4*)&S4[ii][l][co*8])[0] = make_float4(sacc[ii][0],sacc[ii][1],sacc[ii][2],sacc[ii][3]);
      ((float4*)&S4[ii][l][co*8])[1] = make_float4(sacc[ii][4],sacc[ii][5],sacc[ii][6],sacc[ii][7]);
    }
  }
  if (t < 128){
    int ii = t>>5, j = t&31;
    float dx = t3s[i0+ii][0]-t3s[j][0]+1e-8f;
    float dy = t3s[i0+ii][1]-t3s[j][1]+1e-8f;
    float dz = t3s[i0+ii][2]-t3s[j][2]+1e-8f;
    dsm[ii][j] = sqrtf(dx*dx+dy*dy+dz*dz);
  }
  __syncthreads();

  int wave = t >> 6, lane = t & 63;
  int c0 = lane*2;
  float2 bgp = *(const float2*)&bgs[c0];
  float2 bdp = *(const float2*)&bds[c0];
  float4 wt0 = *(const float4*)&wts[c0][0];
  float4 wt1 = *(const float4*)&wts[c0+1][0];

  for (int ii=0; ii<4; ii++){
    // rbf fill (windowed, exact to fp32) for this i
    {
      int r = t >> 2, jb = (t&3)*8;
      #pragma unroll
      for (int u=0;u<8;u++){
        int j = jb+u;
        float d = dsm[ii][j];
        int r0 = r0_of(d);
        float val = 0.f;
        if (r >= r0 && r < r0+16){
          float dd = (d - (float)r*RBF_STEP)*RBF_INVSIG;
          val = __expf(-dd*dd);
        }
        rbfs[r][j] = val;
      }
    }
    __syncthreads();

    #pragma unroll
    for (int itp=0; itp<2; itp++){
      int jg = wave + itp*4;
      int j0 = jg*4;
      float4 dv = *(const float4*)&dsm[ii][j0];
      int r00=r0_of(dv.x), r01=r0_of(dv.y), r02=r0_of(dv.z), r03=r0_of(dv.w);
      int rmin = min(min(r00,r01),min(r02,r03));
      int rmax = max(max(r00,r01),max(r02,r03)) + 16;
      rmin = __builtin_amdgcn_readfirstlane(rmin);
      rmax = __builtin_amdgcn_readfirstlane(rmax);

      float ga[4][2], da[4][2];
      #pragma unroll
      for (int a=0;a<4;a++){ ga[a][0]=0.f; ga[a][1]=0.f; da[a][0]=0.f; da[a][1]=0.f; }

      #pragma unroll
      for (int l=0;l<16;l++){
        float4 e2v = *(const float4*)&e2T[l][j0];
        float2 sv  = *(const float2*)&S4[ii][l][c0];
        ga[0][0]+=e2v.x*sv.x; ga[0][1]+=e2v.x*sv.y;
        ga[1][0]+=e2v.y*sv.x; ga[1][1]+=e2v.y*sv.y;
        ga[2][0]+=e2v.z*sv.x; ga[2][1]+=e2v.z*sv.y;
        ga[3][0]+=e2v.w*sv.x; ga[3][1]+=e2v.w*sv.y;
      }
      for (int r=rmin;r<rmax;r++){
        float4 rv = *(const float4*)&rbfs[r][j0];
        unsigned int wp = wdu[r][lane];
        float w0 = bfl(wp), w1 = bfh(wp);
        da[0][0]+=rv.x*w0; da[0][1]+=rv.x*w1;
        da[1][0]+=rv.y*w0; da[1][1]+=rv.y*w1;
        da[2][0]+=rv.z*w0; da[2][1]+=rv.z*w1;
        da[3][0]+=rv.w*w0; da[3][1]+=rv.w*w1;
      }
      float bp[4][4];
      #pragma unroll
      for (int jj=0;jj<4;jj++){
        float x0 = sigm(ga[jj][0]+bgp.x) * (da[jj][0]+bdp.x);
        float x1 = sigm(ga[jj][1]+bgp.y) * (da[jj][1]+bdp.y);
        bp[jj][0] = x0*wt0.x + x1*wt1.x;
        bp[jj][1] = x0*wt0.y + x1*wt1.y;
        bp[jj][2] = x0*wt0.z + x1*wt1.z;
        bp[jj][3] = x0*wt0.w + x1*wt1.w;
      }
      #pragma unroll
      for (int m=32;m>=1;m>>=1){
        #pragma unroll
        for (int jj=0;jj<4;jj++){
          #pragma unroll
          for (int h=0;h<4;h++) bp[jj][h] += __shfl_xor(bp[jj][h], m);
        }
      }
      if (lane==0){
        float* dst = biasw + ((((size_t)n*KKN)+(i0+ii))*KKN + j0)*NH;
        ((float4*)dst)[0] = make_float4(bp[0][0],bp[0][1],bp[0][2],bp[0][3]);
        ((float4*)dst)[1] = make_float4(bp[1][0],bp[1][1],bp[1][2],bp[1][3]);
        ((float4*)dst)[2] = make_float4(bp[2][0],bp[2][1],bp[2][2],bp[2][3]);
        ((float4*)dst)[3] = make_float4(bp[3][0],bp[3][1],bp[3][2],bp[3][3]);
      }
    }
    __syncthreads();
  }
}

// ---------- K3: per-node QKV + attention + ogate + out projection ----------
// Manual smem arena (48 KB) with explicit lifetimes:
//   [0,8K)    z bf16          phase1-2            } aliased by bias f32 [0,16K)
//   [8K,16K)  wtile bf16pk    phase2 staging      }   after phase2
//   [16K,24K) q bf16          phase2->scores      aliased by o bf16 after scores
//   [24K,32K) k bf16          phase2->scores      aliased by w2 f32 (4K) in phase4
//   [32K,40K) v bf16          phase2->PV
//   [40K,48K) ogs bf16        phase2->phase4
__global__ __launch_bounds__(256) void k3_attn(
    const unsigned short* __restrict__ zw, const float* __restrict__ biasw,
    const float* __restrict__ wq, const float* __restrict__ bq,
    const float* __restrict__ wkv, const float* __restrict__ bkv,
    const float* __restrict__ wout, const float* __restrict__ bout,
    const float* __restrict__ wog, const float* __restrict__ bog,
    float* __restrict__ out)
{
  int n = blockIdx.x, t = threadIdx.x;

  __shared__ __align__(16) char smem[49152];
  unsigned short* zbf  = (unsigned short*)smem;           // [32][128]
  unsigned int*   wtile = (unsigned int*)(smem + 8192);   // [8][256]
  unsigned short* qbf  = (unsigned short*)(smem + 16384); // [32][128]
  unsigned short* kbf  = (unsigned short*)(smem + 24576); // [32][128]
  unsigned short* vbf  = (unsigned short*)(smem + 32768); // [32][128]
  unsigned short* ogsb = (unsigned short*)(smem + 40960); // [32][128]
  float*          biasl = (float*)smem;                   // [4096] after phase2
  unsigned short* obf  = qbf;                             // [32][128] after scores
  float*          w2   = (float*)(smem + 24576);          // [1024] phase4 staging

  // phase1: load z (bf16) for this node
  {
    const uint4* src = (const uint4*)(zw + (size_t)n*KKN*CZ);
    ((uint4*)zbf)[t]       = src[t];
    ((uint4*)zbf)[t+256]   = src[t+256];
  }

  // phase2: [32,128] @ [128, 512] (q|k|v|og), weights staged bf16 in LDS
  int ig = t >> 4, cs = t & 15;      // rows ig*2, ig*2+1 ; cols cs*32..+32
  float acc[2][32];
  #pragma unroll
  for (int a=0;a<2;a++)
    #pragma unroll
    for (int u=0;u<32;u++) acc[a][u]=0.f;

  for (int kt=0; kt<16; kt++){
    { // stage 8 rows x 512 cols (bf16-packed), 16 values/thread
      int s = t*16;
      int krow = s >> 9, c = s & 511;
      int gk = kt*8 + krow;
      const float* src;
      if (c < 128) src = wq + (size_t)gk*128 + c;
      else if (c < 384) src = wkv + (size_t)gk*256 + (c-128);
      else src = wog + (size_t)gk*128 + (c-384);
      float4 f0=((const float4*)src)[0], f1=((const float4*)src)[1];
      float4 f2=((const float4*)src)[2], f3=((const float4*)src)[3];
      unsigned int p[8];
      p[0]=packbf(f0.x,f0.y); p[1]=packbf(f0.z,f0.w);
      p[2]=packbf(f1.x,f1.y); p[3]=packbf(f1.z,f1.w);
      p[4]=packbf(f2.x,f2.y); p[5]=packbf(f2.z,f2.w);
      p[6]=packbf(f3.x,f3.y); p[7]=packbf(f3.z,f3.w);
      uint4* dp = (uint4*)&wtile[krow*256 + (c>>1)];
      dp[0] = make_uint4(p[0],p[1],p[2],p[3]);
      dp[1] = make_uint4(p[4],p[5],p[6],p[7]);
    }
    __syncthreads();
    #pragma unroll
    for (int kk=0;kk<8;kk++){
      float z0 = bfl((unsigned int)zbf[(ig*2)*128   + kt*8+kk]);
      float z1 = bfl((unsigned int)zbf[(ig*2+1)*128 + kt*8+kk]);
      unsigned int ua[16];
      const uint4* wr4 = (const uint4*)&wtile[kk*256 + cs*16];
      *(uint4*)&ua[0]=wr4[0]; *(uint4*)&ua[4]=wr4[1];
      *(uint4*)&ua[8]=wr4[2]; *(uint4*)&ua[12]=wr4[3];
      #pragma unroll
      for (int u=0;u<16;u++){
        float wa = bfl(ua[u]), wb2 = bfh(ua[u]);
        acc[0][2*u]   += z0*wa; acc[0][2*u+1] += z0*wb2;
        acc[1][2*u]   += z1*wa; acc[1][2*u+1] += z1*wb2;
      }
    }
    __syncthreads();
  }
  // epilogue: add biases, sigmoid for og, store bf16 row-major
  {
    int seg = cs >> 2;               // 0=q 1=k 2=v 3=og
    int gc0 = cs*32;
    int lc0 = gc0 & 127;
    #pragma unroll
    for (int ii=0; ii<2; ii++){
      int i = ig*2+ii;
      unsigned int pk[16];
      #pragma unroll
      for (int u=0;u<16;u++){
        int gc = gc0 + 2*u;
        float v0 = acc[ii][2*u], v1 = acc[ii][2*u+1];
        if (seg==0){ v0 += bq[gc]; v1 += bq[gc+1]; }
        else if (seg==3){ v0 = sigm(v0 + bog[gc-384]); v1 = sigm(v1 + bog[gc-383]); }
        else { v0 += bkv[gc-128]; v1 += bkv[gc-127]; }
        pk[u] = packbf(v0,v1);
      }
      unsigned short* dst = (seg==0)? qbf : (seg==1)? kbf : (seg==2)? vbf : ogsb;
      uint4* dp = (uint4*)(dst + i*128 + lc0);
      dp[0]=make_uint4(pk[0],pk[1],pk[2],pk[3]);
      dp[1]=make_uint4(pk[4],pk[5],pk[6],pk[7]);
      dp[2]=make_uint4(pk[8],pk[9],pk[10],pk[11]);
      dp[3]=make_uint4(pk[12],pk[13],pk[14],pk[15]);
    }
  }
  // load bias tensor (16 KB) over dead z+wtile region
  {
    const float4* src = (const float4*)(biasw + (size_t)n*4096);
    #pragma unroll
    for (int u=0;u<4;u++) ((float4*)biasl)[t + u*256] = src[t + u*256];
  }
  __syncthreads();

  // phase3: attention. wave = head; lane -> (i, j-half)
  int h = t >> 6;
  int lane = t & 63;
  int i = lane >> 1, jh = lane & 1, j0 = jh*16;
  float sc[16];
  {
    float qreg[32];
    #pragma unroll
    for (int dq=0;dq<4;dq++){
      uint4 qa = *(const uint4*)&qbf[i*128 + h*32 + dq*8];
      unsigned int qu[4] = {qa.x,qa.y,qa.z,qa.w};
      #pragma unroll
      for (int u=0;u<4;u++){ qreg[dq*8+2*u]=bfl(qu[u]); qreg[dq*8+2*u+1]=bfh(qu[u]); }
    }
    #pragma unroll
    for (int jj=0;jj<16;jj++){
      int j = j0+jj;
      unsigned int ka[16];
      const uint4* kr = (const uint4*)&kbf[j*128 + h*32];
      *(uint4*)&ka[0]=kr[0]; *(uint4*)&ka[4]=kr[1];
      *(uint4*)&ka[8]=kr[2]; *(uint4*)&ka[12]=kr[3];
      float s = 0.f;
      #pragma unroll
      for (int u=0;u<16;u++) s += qreg[2*u]*bfl(ka[u]) + qreg[2*u+1]*bfh(ka[u]);
      sc[jj] = s*0.17677669529663687f + biasl[(i*32+j)*4 + h];
    }
  }
  // softmax over 32 (16 local + partner lane)
  {
    float mx = sc[0];
    #pragma unroll
    for (int jj=1;jj<16;jj++) mx = fmaxf(mx, sc[jj]);
    mx = fmaxf(mx, __shfl_xor(mx,1));
    float sum = 0.f;
    #pragma unroll
    for (int jj=0;jj<16;jj++){ sc[jj] = __expf(sc[jj]-mx); sum += sc[jj]; }
    sum += __shfl_xor(sum,1);
    float inv = 1.0f/sum;
    #pragma unroll
    for (int jj=0;jj<16;jj++) sc[jj] *= inv;
  }
  // all waves must finish reading q/k/bias before o overwrites qbf
  __syncthreads();
  // PV: lane reinterpreted as (i, d-half)
  {
    int dbase = h*32 + jh*16;
    float o16[16];
    #pragma unroll
    for (int u=0;u<16;u++) o16[u]=0.f;
    #pragma unroll
    for (int j=0;j<32;j++){
      float pj = __shfl(sc[j & 15], (lane & 62) | (j >> 4));
      unsigned int va[8];
      const uint4* vr = (const uint4*)&vbf[j*128 + dbase];
      *(uint4*)&va[0]=vr[0]; *(uint4*)&va[4]=vr[1];
      #pragma unroll
      for (int u=0;u<8;u++){ o16[2*u] += pj*bfl(va[u]); o16[2*u+1] += pj*bfh(va[u]); }
    }
    #pragma unroll
    for (int u=0;u<16;u++){
      int c = dbase + u;
      obf[i*128 + ((c + 4*i) & 127)] = f2bf(o16[u]);
    }
  }
  __syncthreads();

  // phase4: out = (o * ogs) @ w_out + b_out ; w2 staging over dead kbf
  {
    int i4 = t >> 3, cs4 = t & 7;    // cols cs4*16..+16
    float acc4[16];
    #pragma unroll
    for (int u=0;u<16;u++) acc4[u]=0.f;
    for (int ct=0; ct<16; ct++){
      ((float4*)w2)[t] = ((const float4*)(wout + (size_t)ct*1024))[t];
      __syncthreads();
      #pragma unroll
      for (int kk=0;kk<8;kk++){
        int c = ct*8+kk;
        float y = bfl((unsigned int)obf[i4*128 + ((c + 4*i4)&127)]) *
                  bfl((unsigned int)ogsb[i4*128 + c]);
        const float4* wr2 = (const float4*)(w2 + kk*128 + cs4*16);
        float4 w0=wr2[0], w1=wr2[1], w2v=wr2[2], w3=wr2[3];
        acc4[0]+=y*w0.x; acc4[1]+=y*w0.y; acc4[2]+=y*w0.z; acc4[3]+=y*w0.w;
        acc4[4]+=y*w1.x; acc4[5]+=y*w1.y; acc4[6]+=y*w1.z; acc4[7]+=y*w1.w;
        acc4[8]+=y*w2v.x; acc4[9]+=y*w2v.y; acc4[10]+=y*w2v.z; acc4[11]+=y*w2v.w;
        acc4[12]+=y*w3.x; acc4[13]+=y*w3.y; acc4[14]+=y*w3.z; acc4[15]+=y*w3.w;
      }
      __syncthreads();
    }
    float* orow = out + ((size_t)n*KKN + i4)*CZ + cs4*16;
    const float4* bo4 = (const float4*)(bout + cs4*16);
    #pragma unroll
    for (int u=0;u<4;u++){
      float4 bv = bo4[u];
      ((float4*)orow)[u] = make_float4(acc4[4*u]+bv.x, acc4[4*u+1]+bv.y,
                                       acc4[4*u+2]+bv.z, acc4[4*u+3]+bv.w);
    }
  }
}

// ---------- launch ----------
extern "C" void kernel_launch(void* const* d_in, const int* in_sizes, int n_in,
                              void* d_out, int out_size, void* d_ws, size_t ws_size,
                              hipStream_t stream)
{
  const float* nf  = (const float*)d_in[0];
  const float* tr  = (const float*)d_in[1];
  const float* ef  = (const float*)d_in[2];
  const long long* ei = (const long long*)d_in[3];
  const float* wl  = (const float*)d_in[4];  const float* bl  = (const float*)d_in[5];
  const float* wr  = (const float*)d_in[6];  const float* br  = (const float*)d_in[7];
  const float* wbg = (const float*)d_in[8];  const float* bbg = (const float*)d_in[9];
  const float* wdi = (const float*)d_in[10]; const float* bdi = (const float*)d_in[11];
  const float* wtb = (const float*)d_in[12];
  const float* lng = (const float*)d_in[13]; const float* lnb = (const float*)d_in[14];
  const float* wq  = (const float*)d_in[15]; const float* bq  = (const float*)d_in[16];
  const float* wkv = (const float*)d_in[17]; const float* bkv = (const float*)d_in[18];
  const float* wo  = (const float*)d_in[19]; const float* bo  = (const float*)d_in[20];
  const float* wog = (const float*)d_in[21]; const float* bog = (const float*)d_in[22];
  float* outp = (float*)d_out;
  float* ws = (float*)d_ws;
  float* nlw = ws;                    // 12288 floats
  float* nrw = ws + 12288;            // 12288 floats
  float* biasw = ws + 24576;          // 768*32*32*4 = 3145728 floats [n][i][j][h]
  unsigned short* zw = (unsigned short*)(ws + 24576 + 3145728);  // E*128 bf16

  hipLaunchKernelGGL(k1_pre, dim3(1632), dim3(256), 0, stream,
                     nf, ef, wl, bl, wr, br, lng, lnb, nlw, nrw, zw);
  hipLaunchKernelGGL(k2_bias, dim3(6144), dim3(256), 0, stream,
                     ei, tr, nlw, nrw, wbg, bbg, wdi, bdi, wtb, biasw);
  hipLaunchKernelGGL(k3_attn, dim3(768), dim3(256), 0, stream,
                     zw, biasw, wq, bq, wkv, bkv, wo, bo, wog, bog, outp);
}

// Round 3
// 514.858 us; speedup vs baseline: 1.6125x; 1.6125x over previous
//
#include <hip/hip_runtime.h>

// Problem constants
#define NN   768
#define KKN  32
#define CS   384
#define CZ   128
#define CG   16
#define NH   4
#define DHD  32
#define NRBF 64
#define EE   (NN*KKN)

#define RBF_STEP    (20.0f/63.0f)
#define RBF_INVSTEP (63.0f/20.0f)
#define RBF_INVSIG  3.2f            // 1/0.3125

typedef __attribute__((ext_vector_type(8))) short bf16x8;
typedef __attribute__((ext_vector_type(4))) float f32x4;

// ---------- helpers ----------
__device__ __forceinline__ unsigned short f2bf(float f){
  unsigned int u = __float_as_uint(f);
  u += 0x7FFFu + ((u >> 16) & 1u);
  return (unsigned short)(u >> 16);
}
__device__ __forceinline__ float bfl(unsigned int u){ return __uint_as_float(u << 16); }
__device__ __forceinline__ float bfh(unsigned int u){ return __uint_as_float(u & 0xFFFF0000u); }
__device__ __forceinline__ unsigned int packbf(float a, float b){
  return (unsigned int)f2bf(a) | ((unsigned int)f2bf(b) << 16);
}
__device__ __forceinline__ float sigm(float x){ return 1.0f/(1.0f + __expf(-x)); }
__device__ __forceinline__ int r0_of(float d){
  int c = (int)floorf(d*RBF_INVSTEP + 0.5f) - 8;
  c = c < 0 ? 0 : c;
  return c > 48 ? 48 : c;
}

// ---------- K1: nl/nr projections + LayerNorm(edge_features) -> bf16 z ----------
__global__ __launch_bounds__(256) void k1_pre(
    const float* __restrict__ nf, const float* __restrict__ ef,
    const float* __restrict__ wl, const float* __restrict__ bl,
    const float* __restrict__ wr, const float* __restrict__ br,
    const float* __restrict__ lng, const float* __restrict__ lnb,
    float* __restrict__ nlw, float* __restrict__ nrw,
    unsigned short* __restrict__ zw)
{
  int b = blockIdx.x, t = threadIdx.x;
  if (b < 1536){
    int rl = t >> 4, l16 = t & 15;
    size_t e = (size_t)b*16 + rl;
    const float4* row = (const float4*)(ef + e*CZ);
    float4 x0 = row[l16*2], x1 = row[l16*2+1];
    float v[8] = {x0.x,x0.y,x0.z,x0.w,x1.x,x1.y,x1.z,x1.w};
    float s = 0.f, q = 0.f;
    #pragma unroll
    for (int u=0;u<8;u++){ s += v[u]; q += v[u]*v[u]; }
    #pragma unroll
    for (int m=1;m<16;m<<=1){ s += __shfl_xor(s,m); q += __shfl_xor(q,m); }
    float mean = s*(1.f/128.f);
    float var  = q*(1.f/128.f) - mean*mean;
    float rs = rsqrtf(var + 1e-5f);
    int c0 = l16*8;
    unsigned int pk[4];
    #pragma unroll
    for (int u=0;u<4;u++){
      float z0 = (v[2*u]  -mean)*rs*lng[c0+2*u]   + lnb[c0+2*u];
      float z1 = (v[2*u+1]-mean)*rs*lng[c0+2*u+1] + lnb[c0+2*u+1];
      pk[u] = packbf(z0,z1);
    }
    ((uint4*)(zw + e*CZ))[l16] = make_uint4(pk[0],pk[1],pk[2],pk[3]);
  } else {
    int gid = (b-1536)*256 + t;           // 0..24575
    int side = (gid >= 12288) ? 1 : 0;
    int idx = gid - side*12288;
    int nd = idx >> 4, c = idx & 15;
    const float* w = side ? wr : wl;
    float acc = side ? br[c] : bl[c];
    const float* nrow = nf + (size_t)nd*CS;
    #pragma unroll 4
    for (int k=0;k<CS;k++) acc += nrow[k]*w[k*CG+c];
    (side? nrw : nlw)[idx] = acc;
  }
}

// ---------- K2 (MFMA): bias[n,i,j,h] per (node, 4-i chunk) ----------
// Transposed-operand scheme (all LDS operands K-contiguous, padded rows):
//   ga_T[c,j] = sum_l  S_T[c][l] * e2b[j][l]      (K=32, l>=16 zeroed)
//   da_T[c,j] = sum_r  wdT[c][r] * rbfb[j][r]     (K=64 dense, windowed rbf)
//   X[j][c]   = sigmoid(ga+bg[c]) * (da+bd[c])    (bf16)
//   biasT[h,j]= sum_c  wtT[h][c] * X[j][c]        (K=128)
__global__ __launch_bounds__(256) void k2_bias(
    const long long* __restrict__ eidx, const float* __restrict__ trans,
    const float* __restrict__ nlw, const float* __restrict__ nrw,
    const float* __restrict__ wb, const float* __restrict__ bg,
    const float* __restrict__ wd, const float* __restrict__ bd,
    const float* __restrict__ wt,
    float* __restrict__ biasw)
{
  int n = blockIdx.x >> 3, chunk = blockIdx.x & 7;
  int i0 = chunk*4;
  int t = threadIdx.x;
  int wave = t>>6, lane = t&63, q = lane>>4, l15 = lane&15;

  __shared__ __align__(16) unsigned short wdT [128*72];  // 18.0 KB  [c][r]
  __shared__ __align__(16) unsigned short ST  [128*40];  // 10.0 KB  [c][l] (l>=16 zero)
  __shared__ __align__(16) unsigned short Xb  [32*136];  //  8.5 KB  [j][c]
  __shared__ __align__(16) unsigned short rbfb[32*72];   //  4.5 KB  [j][r]
  __shared__ __align__(16) unsigned short wtT [16*136];  //  4.25 KB [h][c]
  __shared__ __align__(16) unsigned short e2b [32*40];   //  2.5 KB  [j][l] (l>=16 zero)
  __shared__ __align__(16) float bgs[128];
  __shared__ __align__(16) float bds[128];
  __shared__ __align__(16) float t3s[32][4];
  __shared__ __align__(16) float dsm[4][32];
  __shared__ float e1c[4][16];
  __shared__ int srcs[32];

  // ---- ph0a: srcs, wd transpose->bf16, wt transpose, biases, zero pads ----
  if (t < 32) srcs[t] = (int)eidx[(size_t)n*KKN + t];
  {
    int c = t>>1, rh = t&1, r0b = rh*32;
    float vr[32];
    #pragma unroll
    for (int r=0;r<32;r++) vr[r] = wd[(size_t)(r0b+r)*CZ + c];
    #pragma unroll
    for (int g=0; g<4; g++){
      *(uint4*)&wdT[c*72 + r0b + g*8] = make_uint4(
        packbf(vr[g*8],vr[g*8+1]), packbf(vr[g*8+2],vr[g*8+3]),
        packbf(vr[g*8+4],vr[g*8+5]), packbf(vr[g*8+6],vr[g*8+7]));
    }
  }
  if (t < 128){
    bgs[t]=bg[t]; bds[t]=bd[t];
    float4 wv = ((const float4*)wt)[t];
    wtT[0*136+t]=f2bf(wv.x); wtT[1*136+t]=f2bf(wv.y);
    wtT[2*136+t]=f2bf(wv.z); wtT[3*136+t]=f2bf(wv.w);
  }
  if (t < 96){ int j=t/3, ch=t-3*j; *(uint4*)&e2b[j*40+16+ch*8]=make_uint4(0,0,0,0); }
  { int c=t/3, ch=t-3*c; *(uint4*)&ST[c*40+16+ch*8]=make_uint4(0,0,0,0); }
  if (t < 128){ int idx=t+256; int c=idx/3, ch=idx-3*c; *(uint4*)&ST[c*40+16+ch*8]=make_uint4(0,0,0,0); }
  __syncthreads();
  // ---- ph0b: gathers that need srcs ----
  if (t < 64){
    int j=t>>1, lh=t&1;
    const float* p = nrw + srcs[j]*CG + lh*8;
    *(uint4*)&e2b[j*40 + lh*8] = make_uint4(
      packbf(p[0],p[1]),packbf(p[2],p[3]),packbf(p[4],p[5]),packbf(p[6],p[7]));
  }
  if (t >= 64 && t < 128){ int tt=t-64; int ii=tt>>4, k=tt&15; e1c[ii][k] = nlw[srcs[i0+ii]*CG+k]; }
  if (t >= 128 && t < 160){ int j=t-128; int s=srcs[j];
    t3s[j][0]=trans[s*3]; t3s[j][1]=trans[s*3+1]; t3s[j][2]=trans[s*3+2]; }
  __syncthreads();
  // ---- ph0c: distances + S for all 4 i into registers (wb read ONCE/block) ----
  if (t < 128){
    int ii=t>>5, j=t&31;
    float dx=t3s[i0+ii][0]-t3s[j][0]+1e-8f;
    float dy=t3s[i0+ii][1]-t3s[j][1]+1e-8f;
    float dz=t3s[i0+ii][2]-t3s[j][2]+1e-8f;
    dsm[ii][j]=sqrtf(dx*dx+dy*dy+dz*dz);
  }
  float S4i[4][8];
  #pragma unroll
  for(int a=0;a<4;a++){
    #pragma unroll
    for(int u=0;u<8;u++) S4i[a][u]=0.f;
  }
  {
    int c=t>>1, l0=(t&1)*8;
    for (int k=0;k<16;k++){
      float ev0=e1c[0][k], ev1=e1c[1][k], ev2=e1c[2][k], ev3=e1c[3][k];
      #pragma unroll
      for (int u=0;u<8;u++){
        float w = wb[(size_t)(k*CG + l0 + u)*CZ + c];
        S4i[0][u]+=ev0*w; S4i[1][u]+=ev1*w; S4i[2][u]+=ev2*w; S4i[3][u]+=ev3*w;
      }
    }
  }
  __syncthreads();

  // ---- per-i: stage S_T + rbf, MFMA ga/da, epilogue X, final bias MFMA ----
  #pragma unroll
  for (int ii=0; ii<4; ii++){
    { // S_T(i) write (bf16)
      int c=t>>1, l0=(t&1)*8;
      *(uint4*)&ST[c*40+l0] = make_uint4(
        packbf(S4i[ii][0],S4i[ii][1]), packbf(S4i[ii][2],S4i[ii][3]),
        packbf(S4i[ii][4],S4i[ii][5]), packbf(S4i[ii][6],S4i[ii][7]));
    }
    { // windowed rbf fill (zeros outside window), rows j, cols r in [0,72)
      int jr=t>>3, sl=t&7;
      float d = dsm[ii][jr];
      int r0 = r0_of(d);
      #pragma unroll
      for (int u=0;u<9;u++){
        int r = sl*9+u;
        float val=0.f;
        if (r>=r0 && r<r0+16){ float dd=(d-(float)r*RBF_STEP)*RBF_INVSIG; val=__expf(-dd*dd); }
        rbfb[jr*72+r]=f2bf(val);
      }
    }
    __syncthreads();

    // wave w owns c in [32w,32w+32): mtiles {2w,2w+1}, ntiles {0,1}
    f32x4 zero4 = {0.f,0.f,0.f,0.f};
    f32x4 ga[2][2], da[2][2];
    #pragma unroll
    for(int a=0;a<2;a++){
      #pragma unroll
      for(int b2=0;b2<2;b2++){ ga[a][b2]=zero4; da[a][b2]=zero4; }
    }
    {
      bf16x8 bE[2];
      #pragma unroll
      for(int nt=0;nt<2;nt++) bE[nt] = *(const bf16x8*)&e2b[(nt*16+l15)*40 + q*8];
      #pragma unroll
      for(int mt=0;mt<2;mt++){
        bf16x8 aS = *(const bf16x8*)&ST[(wave*32+mt*16+l15)*40 + q*8];
        #pragma unroll
        for(int nt=0;nt<2;nt++)
          ga[mt][nt] = __builtin_amdgcn_mfma_f32_16x16x32_bf16(aS, bE[nt], ga[mt][nt], 0,0,0);
      }
      #pragma unroll
      for(int ks=0;ks<2;ks++){
        bf16x8 bR[2];
        #pragma unroll
        for(int nt=0;nt<2;nt++) bR[nt] = *(const bf16x8*)&rbfb[(nt*16+l15)*72 + ks*32 + q*8];
        #pragma unroll
        for(int mt=0;mt<2;mt++){
          bf16x8 aW = *(const bf16x8*)&wdT[(wave*32+mt*16+l15)*72 + ks*32 + q*8];
          #pragma unroll
          for(int nt=0;nt<2;nt++)
            da[mt][nt] = __builtin_amdgcn_mfma_f32_16x16x32_bf16(aW, bR[nt], da[mt][nt], 0,0,0);
        }
      }
    }
    // epilogue: X[j][c] = sigmoid(ga+bg)*(da+bd), bf16
    #pragma unroll
    for(int mt=0;mt<2;mt++){
      int c0 = wave*32 + mt*16 + q*4;
      float4 bgv = *(const float4*)&bgs[c0];
      float4 bdv = *(const float4*)&bds[c0];
      #pragma unroll
      for(int nt=0;nt<2;nt++){
        float x0 = sigm(ga[mt][nt][0]+bgv.x)*(da[mt][nt][0]+bdv.x);
        float x1 = sigm(ga[mt][nt][1]+bgv.y)*(da[mt][nt][1]+bdv.y);
        float x2 = sigm(ga[mt][nt][2]+bgv.z)*(da[mt][nt][2]+bdv.z);
        float x3 = sigm(ga[mt][nt][3]+bgv.w)*(da[mt][nt][3]+bdv.w);
        *(uint2*)&Xb[(nt*16+l15)*136 + c0] = make_uint2(packbf(x0,x1), packbf(x2,x3));
      }
    }
    __syncthreads();

    // final: biasT[h][j] = wtT[h][:] . Xb[j][:], waves 0,1 (j-halves)
    if (wave < 2){
      f32x4 bacc = zero4;
      #pragma unroll
      for(int ks=0;ks<4;ks++){
        bf16x8 aT = *(const bf16x8*)&wtT[l15*136 + ks*32 + q*8];
        bf16x8 bX = *(const bf16x8*)&Xb[(wave*16+l15)*136 + ks*32 + q*8];
        bacc = __builtin_amdgcn_mfma_f32_16x16x32_bf16(aT,bX,bacc,0,0,0);
      }
      if (q==0){   // rows h=0..3 live in quad 0 regs
        int j = wave*16 + l15;
        float* dst = biasw + (((size_t)n*KKN + (i0+ii))*KKN + j)*NH;
        *(float4*)dst = make_float4(bacc[0],bacc[1],bacc[2],bacc[3]);
      }
    }
  }
}

// ---------- K3: per-node QKV + attention + ogate + out projection ----------
__global__ __launch_bounds__(256) void k3_attn(
    const unsigned short* __restrict__ zw, const float* __restrict__ biasw,
    const float* __restrict__ wq, const float* __restrict__ bq,
    const float* __restrict__ wkv, const float* __restrict__ bkv,
    const float* __restrict__ wout, const float* __restrict__ bout,
    const float* __restrict__ wog, const float* __restrict__ bog,
    float* __restrict__ out)
{
  int n = blockIdx.x, t = threadIdx.x;

  __shared__ __align__(16) char smem[49152];
  unsigned short* zbf  = (unsigned short*)smem;           // [32][128]
  unsigned int*   wtile = (unsigned int*)(smem + 8192);   // [8][256]
  unsigned short* qbf  = (unsigned short*)(smem + 16384); // [32][128]
  unsigned short* kbf  = (unsigned short*)(smem + 24576); // [32][128]
  unsigned short* vbf  = (unsigned short*)(smem + 32768); // [32][128]
  unsigned short* ogsb = (unsigned short*)(smem + 40960); // [32][128]
  float*          biasl = (float*)smem;                   // [4096] after phase2
  unsigned short* obf  = qbf;                             // [32][128] after scores
  float*          w2   = (float*)(smem + 24576);          // [1024] phase4 staging

  {
    const uint4* src = (const uint4*)(zw + (size_t)n*KKN*CZ);
    ((uint4*)zbf)[t]       = src[t];
    ((uint4*)zbf)[t+256]   = src[t+256];
  }

  int ig = t >> 4, cs = t & 15;
  float acc[2][32];
  #pragma unroll
  for (int a=0;a<2;a++){
    #pragma unroll
    for (int u=0;u<32;u++) acc[a][u]=0.f;
  }

  for (int kt=0; kt<16; kt++){
    {
      int s = t*16;
      int krow = s >> 9, c = s & 511;
      int gk = kt*8 + krow;
      const float* src;
      if (c < 128) src = wq + (size_t)gk*128 + c;
      else if (c < 384) src = wkv + (size_t)gk*256 + (c-128);
      else src = wog + (size_t)gk*128 + (c-384);
      float4 f0=((const float4*)src)[0], f1=((const float4*)src)[1];
      float4 f2=((const float4*)src)[2], f3=((const float4*)src)[3];
      unsigned int p[8];
      p[0]=packbf(f0.x,f0.y); p[1]=packbf(f0.z,f0.w);
      p[2]=packbf(f1.x,f1.y); p[3]=packbf(f1.z,f1.w);
      p[4]=packbf(f2.x,f2.y); p[5]=packbf(f2.z,f2.w);
      p[6]=packbf(f3.x,f3.y); p[7]=packbf(f3.z,f3.w);
      uint4* dp = (uint4*)&wtile[krow*256 + (c>>1)];
      dp[0] = make_uint4(p[0],p[1],p[2],p[3]);
      dp[1] = make_uint4(p[4],p[5],p[6],p[7]);
    }
    __syncthreads();
    #pragma unroll
    for (int kk=0;kk<8;kk++){
      float z0 = bfl((unsigned int)zbf[(ig*2)*128   + kt*8+kk]);
      float z1 = bfl((unsigned int)zbf[(ig*2+1)*128 + kt*8+kk]);
      unsigned int ua[16];
      const uint4* wr4 = (const uint4*)&wtile[kk*256 + cs*16];
      *(uint4*)&ua[0]=wr4[0]; *(uint4*)&ua[4]=wr4[1];
      *(uint4*)&ua[8]=wr4[2]; *(uint4*)&ua[12]=wr4[3];
      #pragma unroll
      for (int u=0;u<16;u++){
        float wa = bfl(ua[u]), wb2 = bfh(ua[u]);
        acc[0][2*u]   += z0*wa; acc[0][2*u+1] += z0*wb2;
        acc[1][2*u]   += z1*wa; acc[1][2*u+1] += z1*wb2;
      }
    }
    __syncthreads();
  }
  {
    int seg = cs >> 2;
    int gc0 = cs*32;
    int lc0 = gc0 & 127;
    #pragma unroll
    for (int ii=0; ii<2; ii++){
      int i = ig*2+ii;
      unsigned int pk[16];
      #pragma unroll
      for (int u=0;u<16;u++){
        int gc = gc0 + 2*u;
        float v0 = acc[ii][2*u], v1 = acc[ii][2*u+1];
        if (seg==0){ v0 += bq[gc]; v1 += bq[gc+1]; }
        else if (seg==3){ v0 = sigm(v0 + bog[gc-384]); v1 = sigm(v1 + bog[gc-383]); }
        else { v0 += bkv[gc-128]; v1 += bkv[gc-127]; }
        pk[u] = packbf(v0,v1);
      }
      unsigned short* dst = (seg==0)? qbf : (seg==1)? kbf : (seg==2)? vbf : ogsb;
      uint4* dp = (uint4*)(dst + i*128 + lc0);
      dp[0]=make_uint4(pk[0],pk[1],pk[2],pk[3]);
      dp[1]=make_uint4(pk[4],pk[5],pk[6],pk[7]);
      dp[2]=make_uint4(pk[8],pk[9],pk[10],pk[11]);
      dp[3]=make_uint4(pk[12],pk[13],pk[14],pk[15]);
    }
  }
  {
    const float4* src = (const float4*)(biasw + (size_t)n*4096);
    #pragma unroll
    for (int u=0;u<4;u++) ((float4*)biasl)[t + u*256] = src[t + u*256];
  }
  __syncthreads();

  int h = t >> 6;
  int lane = t & 63;
  int i = lane >> 1, jh = lane & 1, j0 = jh*16;
  float sc[16];
  {
    float qreg[32];
    #pragma unroll
    for (int dq=0;dq<4;dq++){
      uint4 qa = *(const uint4*)&qbf[i*128 + h*32 + dq*8];
      unsigned int qu[4] = {qa.x,qa.y,qa.z,qa.w};
      #pragma unroll
      for (int u=0;u<4;u++){ qreg[dq*8+2*u]=bfl(qu[u]); qreg[dq*8+2*u+1]=bfh(qu[u]); }
    }
    #pragma unroll
    for (int jj=0;jj<16;jj++){
      int j = j0+jj;
      unsigned int ka[16];
      const uint4* kr = (const uint4*)&kbf[j*128 + h*32];
      *(uint4*)&ka[0]=kr[0]; *(uint4*)&ka[4]=kr[1];
      *(uint4*)&ka[8]=kr[2]; *(uint4*)&ka[12]=kr[3];
      float s = 0.f;
      #pragma unroll
      for (int u=0;u<16;u++) s += qreg[2*u]*bfl(ka[u]) + qreg[2*u+1]*bfh(ka[u]);
      sc[jj] = s*0.17677669529663687f + biasl[(i*32+j)*4 + h];
    }
  }
  {
    float mx = sc[0];
    #pragma unroll
    for (int jj=1;jj<16;jj++) mx = fmaxf(mx, sc[jj]);
    mx = fmaxf(mx, __shfl_xor(mx,1));
    float sum = 0.f;
    #pragma unroll
    for (int jj=0;jj<16;jj++){ sc[jj] = __expf(sc[jj]-mx); sum += sc[jj]; }
    sum += __shfl_xor(sum,1);
    float inv = 1.0f/sum;
    #pragma unroll
    for (int jj=0;jj<16;jj++) sc[jj] *= inv;
  }
  __syncthreads();
  {
    int dbase = h*32 + jh*16;
    float o16[16];
    #pragma unroll
    for (int u=0;u<16;u++) o16[u]=0.f;
    #pragma unroll
    for (int j=0;j<32;j++){
      float pj = __shfl(sc[j & 15], (lane & 62) | (j >> 4));
      unsigned int va[8];
      const uint4* vr = (const uint4*)&vbf[j*128 + dbase];
      *(uint4*)&va[0]=vr[0]; *(uint4*)&va[4]=vr[1];
      #pragma unroll
      for (int u=0;u<8;u++){ o16[2*u] += pj*bfl(va[u]); o16[2*u+1] += pj*bfh(va[u]); }
    }
    #pragma unroll
    for (int u=0;u<16;u++){
      int c = dbase + u;
      obf[i*128 + ((c + 4*i) & 127)] = f2bf(o16[u]);
    }
  }
  __syncthreads();

  {
    int i4 = t >> 3, cs4 = t & 7;
    float acc4[16];
    #pragma unroll
    for (int u=0;u<16;u++) acc4[u]=0.f;
    for (int ct=0; ct<16; ct++){
      ((float4*)w2)[t] = ((const float4*)(wout + (size_t)ct*1024))[t];
      __syncthreads();
      #pragma unroll
      for (int kk=0;kk<8;kk++){
        int c = ct*8+kk;
        float y = bfl((unsigned int)obf[i4*128 + ((c + 4*i4)&127)]) *
                  bfl((unsigned int)ogsb[i4*128 + c]);
        const float4* wr2 = (const float4*)(w2 + kk*128 + cs4*16);
        float4 w0=wr2[0], w1=wr2[1], w2v=wr2[2], w3=wr2[3];
        acc4[0]+=y*w0.x; acc4[1]+=y*w0.y; acc4[2]+=y*w0.z; acc4[3]+=y*w0.w;
        acc4[4]+=y*w1.x; acc4[5]+=y*w1.y; acc4[6]+=y*w1.z; acc4[7]+=y*w1.w;
        acc4[8]+=y*w2v.x; acc4[9]+=y*w2v.y; acc4[10]+=y*w2v.z; acc4[11]+=y*w2v.w;
        acc4[12]+=y*w3.x; acc4[13]+=y*w3.y; acc4[14]+=y*w3.z; acc4[15]+=y*w3.w;
      }
      __syncthreads();
    }
    float* orow = out + ((size_t)n*KKN + i4)*CZ + cs4*16;
    const float4* bo4 = (const float4*)(bout + cs4*16);
    #pragma unroll
    for (int u=0;u<4;u++){
      float4 bv = bo4[u];
      ((float4*)orow)[u] = make_float4(acc4[4*u]+bv.x, acc4[4*u+1]+bv.y,
                                       acc4[4*u+2]+bv.z, acc4[4*u+3]+bv.w);
    }
  }
}

// ---------- launch ----------
extern "C" void kernel_launch(void* const* d_in, const int* in_sizes, int n_in,
                              void* d_out, int out_size, void* d_ws, size_t ws_size,
                              hipStream_t stream)
{
  const float* nf  = (const float*)d_in[0];
  const float* tr  = (const float*)d_in[1];
  const float* ef  = (const float*)d_in[2];
  const long long* ei = (const long long*)d_in[3];
  const float* wl  = (const float*)d_in[4];  const float* bl  = (const float*)d_in[5];
  const float* wr  = (const float*)d_in[6];  const float* br  = (const float*)d_in[7];
  const float* wbg = (const float*)d_in[8];  const float* bbg = (const float*)d_in[9];
  const float* wdi = (const float*)d_in[10]; const float* bdi = (const float*)d_in[11];
  const float* wtb = (const float*)d_in[12];
  const float* lng = (const float*)d_in[13]; const float* lnb = (const float*)d_in[14];
  const float* wq  = (const float*)d_in[15]; const float* bq  = (const float*)d_in[16];
  const float* wkv = (const float*)d_in[17]; const float* bkv = (const float*)d_in[18];
  const float* wo  = (const float*)d_in[19]; const float* bo  = (const float*)d_in[20];
  const float* wog = (const float*)d_in[21]; const float* bog = (const float*)d_in[22];
  float* outp = (float*)d_out;
  float* ws = (float*)d_ws;
  float* nlw = ws;                    // 12288 floats
  float* nrw = ws + 12288;            // 12288 floats
  float* biasw = ws + 24576;          // 768*32*32*4 floats [n][i][j][h]
  unsigned short* zw = (unsigned short*)(ws + 24576 + 3145728);  // E*128 bf16

  hipLaunchKernelGGL(k1_pre, dim3(1632), dim3(256), 0, stream,
                     nf, ef, wl, bl, wr, br, lng, lnb, nlw, nrw, zw);
  hipLaunchKernelGGL(k2_bias, dim3(6144), dim3(256), 0, stream,
                     ei, tr, nlw, nrw, wbg, bbg, wdi, bdi, wtb, biasw);
  hipLaunchKernelGGL(k3_attn, dim3(768), dim3(256), 0, stream,
                     zw, biasw, wq, bq, wkv, bkv, wo, bo, wog, bog, outp);
}

// Round 5
// 328.307 us; speedup vs baseline: 2.5287x; 1.5682x over previous
//
#include <hip/hip_runtime.h>

// Problem constants
#define NN   768
#define KKN  32
#define CS   384
#define CZ   128
#define CG   16
#define NH   4
#define DHD  32
#define NRBF 64
#define EE   (NN*KKN)

#define RBF_STEP    (20.0f/63.0f)
#define RBF_INVSTEP (63.0f/20.0f)
#define RBF_INVSIG  3.2f            // 1/0.3125

typedef __attribute__((ext_vector_type(8))) short bf16x8;
typedef __attribute__((ext_vector_type(4))) float f32x4;

// ---------- helpers ----------
__device__ __forceinline__ unsigned short f2bf(float f){
  unsigned int u = __float_as_uint(f);
  u += 0x7FFFu + ((u >> 16) & 1u);
  return (unsigned short)(u >> 16);
}
__device__ __forceinline__ float bfl(unsigned int u){ return __uint_as_float(u << 16); }
__device__ __forceinline__ float bfh(unsigned int u){ return __uint_as_float(u & 0xFFFF0000u); }
__device__ __forceinline__ unsigned int packbf(float a, float b){
  return (unsigned int)f2bf(a) | ((unsigned int)f2bf(b) << 16);
}
__device__ __forceinline__ float sigm(float x){ return 1.0f/(1.0f + __expf(-x)); }
__device__ __forceinline__ int r0_of(float d){
  int c = (int)floorf(d*RBF_INVSTEP + 0.5f) - 8;
  c = c < 0 ? 0 : c;
  return c > 48 ? 48 : c;
}

// ---------- K0: one-time weight transpose/pack into ws ----------
// wqkvogT[512][128] bf16, in-row swizzle: k-block g stored at ((g + c)&15)*8
// woutT [128][128] bf16, same swizzle
// wdT   [128][72]  bf16, plain (k2 layout)      wtT [16][136] bf16 rows 0..3, plain
__global__ __launch_bounds__(256) void k0_prep(
    const float* __restrict__ wq, const float* __restrict__ wkv,
    const float* __restrict__ wog, const float* __restrict__ wout,
    const float* __restrict__ wd, const float* __restrict__ wt,
    unsigned short* __restrict__ wqkvogT, unsigned short* __restrict__ woutT,
    unsigned short* __restrict__ wdT, unsigned short* __restrict__ wtT)
{
  int id = blockIdx.x*256 + threadIdx.x;
  float v[8];
  if (id < 8192){
    int c = id & 511, g = id >> 9;
    const float* src; int ld, col;
    if (c < 128){ src = wq; ld = 128; col = c; }
    else if (c < 384){ src = wkv; ld = 256; col = c-128; }
    else { src = wog; ld = 128; col = c-384; }
    #pragma unroll
    for (int j=0;j<8;j++) v[j] = src[(size_t)(g*8+j)*ld + col];
    *(uint4*)(wqkvogT + c*128 + ((g + c)&15)*8) = make_uint4(
      packbf(v[0],v[1]),packbf(v[2],v[3]),packbf(v[4],v[5]),packbf(v[6],v[7]));
  } else if (id < 10240){
    int l = id - 8192; int c = l & 127, g = l >> 7;
    #pragma unroll
    for (int j=0;j<8;j++) v[j] = wout[(size_t)(g*8+j)*128 + c];
    *(uint4*)(woutT + c*128 + ((g + c)&15)*8) = make_uint4(
      packbf(v[0],v[1]),packbf(v[2],v[3]),packbf(v[4],v[5]),packbf(v[6],v[7]));
  } else if (id < 11392){
    int l = id - 10240; int c = l & 127, g = l >> 7;   // g 0..8
    #pragma unroll
    for (int j=0;j<8;j++) v[j] = (g<8) ? wd[(size_t)(g*8+j)*128 + c] : 0.f;
    *(uint4*)(wdT + c*72 + g*8) = make_uint4(
      packbf(v[0],v[1]),packbf(v[2],v[3]),packbf(v[4],v[5]),packbf(v[6],v[7]));
  } else if (id < 11460){
    int l = id - 11392; int h = l / 17, g = l % 17;
    #pragma unroll
    for (int j=0;j<8;j++){ int cc = g*8+j; v[j] = (cc<128)? wt[cc*4 + h] : 0.f; }
    *(uint4*)(wtT + h*136 + g*8) = make_uint4(
      packbf(v[0],v[1]),packbf(v[2],v[3]),packbf(v[4],v[5]),packbf(v[6],v[7]));
  }
}

// ---------- K1: nl/nr projections + LayerNorm(edge_features) -> bf16 z ----------
__global__ __launch_bounds__(256) void k1_pre(
    const float* __restrict__ nf, const float* __restrict__ ef,
    const float* __restrict__ wl, const float* __restrict__ bl,
    const float* __restrict__ wr, const float* __restrict__ br,
    const float* __restrict__ lng, const float* __restrict__ lnb,
    float* __restrict__ nlw, float* __restrict__ nrw,
    unsigned short* __restrict__ zw)
{
  int b = blockIdx.x, t = threadIdx.x;
  if (b < 1536){
    int rl = t >> 4, l16 = t & 15;
    size_t e = (size_t)b*16 + rl;
    const float4* row = (const float4*)(ef + e*CZ);
    float4 x0 = row[l16*2], x1 = row[l16*2+1];
    float v[8] = {x0.x,x0.y,x0.z,x0.w,x1.x,x1.y,x1.z,x1.w};
    float s = 0.f, q = 0.f;
    #pragma unroll
    for (int u=0;u<8;u++){ s += v[u]; q += v[u]*v[u]; }
    #pragma unroll
    for (int m=1;m<16;m<<=1){ s += __shfl_xor(s,m); q += __shfl_xor(q,m); }
    float mean = s*(1.f/128.f);
    float var  = q*(1.f/128.f) - mean*mean;
    float rs = rsqrtf(var + 1e-5f);
    int c0 = l16*8;
    unsigned int pk[4];
    #pragma unroll
    for (int u=0;u<4;u++){
      float z0 = (v[2*u]  -mean)*rs*lng[c0+2*u]   + lnb[c0+2*u];
      float z1 = (v[2*u+1]-mean)*rs*lng[c0+2*u+1] + lnb[c0+2*u+1];
      pk[u] = packbf(z0,z1);
    }
    ((uint4*)(zw + e*CZ))[l16] = make_uint4(pk[0],pk[1],pk[2],pk[3]);
  } else {
    int gid = (b-1536)*256 + t;           // 0..24575
    int side = (gid >= 12288) ? 1 : 0;
    int idx = gid - side*12288;
    int nd = idx >> 4, c = idx & 15;
    const float* w = side ? wr : wl;
    float acc = side ? br[c] : bl[c];
    const float* nrow = nf + (size_t)nd*CS;
    #pragma unroll 4
    for (int k=0;k<CS;k++) acc += nrow[k]*w[k*CG+c];
    (side? nrw : nlw)[idx] = acc;
  }
}

// ---------- K2 (MFMA): bias[n][h][i][j] per (node, 4-i chunk) ----------
__global__ __launch_bounds__(256) void k2_bias(
    const long long* __restrict__ eidx, const float* __restrict__ trans,
    const float* __restrict__ nlw, const float* __restrict__ nrw,
    const float* __restrict__ wb, const float* __restrict__ bg,
    const unsigned short* __restrict__ wdTg, const float* __restrict__ bd,
    const unsigned short* __restrict__ wtTg,
    float* __restrict__ biasw)
{
  int n = blockIdx.x >> 3, chunk = blockIdx.x & 7;
  int i0 = chunk*4;
  int t = threadIdx.x;
  int wave = t>>6, lane = t&63, q = lane>>4, l15 = lane&15;

  __shared__ __align__(16) unsigned short wdT [128*72];  // 18.0 KB  [c][r]
  __shared__ __align__(16) unsigned short ST  [128*40];  // 10.0 KB  [c][l] (l>=16 zero)
  __shared__ __align__(16) unsigned short Xb  [32*136];  //  8.5 KB  [j][c]
  __shared__ __align__(16) unsigned short rbfb[32*72];   //  4.5 KB  [j][r]
  __shared__ __align__(16) unsigned short wtT [16*136];  //  4.25 KB [h][c]
  __shared__ __align__(16) unsigned short e2b [32*40];   //  2.5 KB  [j][l] (l>=16 zero)
  __shared__ __align__(16) float bgs[128];
  __shared__ __align__(16) float bds[128];
  __shared__ __align__(16) float t3s[32][4];
  __shared__ __align__(16) float dsm[4][32];
  __shared__ float e1c[4][16];
  __shared__ int srcs[32];

  // ---- ph0a: srcs + stage pre-packed wdT/wtT + biases + zero pads ----
  if (t < 32) srcs[t] = (int)eidx[(size_t)n*KKN + t];
  {
    const uint4* s1 = (const uint4*)wdTg;
    uint4* d1 = (uint4*)wdT;
    #pragma unroll
    for (int u=0;u<4;u++) d1[t + u*256] = s1[t + u*256];
    if (t < 128) d1[1024 + t] = s1[1024 + t];
    const uint4* s2 = (const uint4*)wtTg;
    uint4* d2 = (uint4*)wtT;
    d2[t] = s2[t];
    if (t < 16) d2[256 + t] = s2[256 + t];
  }
  if (t < 128){ bgs[t]=bg[t]; bds[t]=bd[t]; }
  if (t < 96){ int j=t/3, ch=t-3*j; *(uint4*)&e2b[j*40+16+ch*8]=make_uint4(0,0,0,0); }
  { int c=t/3, ch=t-3*c; *(uint4*)&ST[c*40+16+ch*8]=make_uint4(0,0,0,0); }
  if (t < 128){ int idx=t+256; int c=idx/3, ch=idx-3*c; *(uint4*)&ST[c*40+16+ch*8]=make_uint4(0,0,0,0); }
  __syncthreads();
  // ---- ph0b: gathers ----
  if (t < 64){
    int j=t>>1, lh=t&1;
    const float* p = nrw + srcs[j]*CG + lh*8;
    *(uint4*)&e2b[j*40 + lh*8] = make_uint4(
      packbf(p[0],p[1]),packbf(p[2],p[3]),packbf(p[4],p[5]),packbf(p[6],p[7]));
  }
  if (t >= 64 && t < 128){ int tt=t-64; int ii=tt>>4, k=tt&15; e1c[ii][k] = nlw[srcs[i0+ii]*CG+k]; }
  if (t >= 128 && t < 160){ int j=t-128; int s=srcs[j];
    t3s[j][0]=trans[s*3]; t3s[j][1]=trans[s*3+1]; t3s[j][2]=trans[s*3+2]; }
  __syncthreads();
  // ---- ph0c: distances + S for all 4 i into registers ----
  if (t < 128){
    int ii=t>>5, j=t&31;
    float dx=t3s[i0+ii][0]-t3s[j][0]+1e-8f;
    float dy=t3s[i0+ii][1]-t3s[j][1]+1e-8f;
    float dz=t3s[i0+ii][2]-t3s[j][2]+1e-8f;
    dsm[ii][j]=sqrtf(dx*dx+dy*dy+dz*dz);
  }
  float S4i[4][8];
  #pragma unroll
  for(int a=0;a<4;a++){
    #pragma unroll
    for(int u=0;u<8;u++) S4i[a][u]=0.f;
  }
  {
    int c=t>>1, l0=(t&1)*8;
    for (int k=0;k<16;k++){
      float ev0=e1c[0][k], ev1=e1c[1][k], ev2=e1c[2][k], ev3=e1c[3][k];
      #pragma unroll
      for (int u=0;u<8;u++){
        float w = wb[(size_t)(k*CG + l0 + u)*CZ + c];
        S4i[0][u]+=ev0*w; S4i[1][u]+=ev1*w; S4i[2][u]+=ev2*w; S4i[3][u]+=ev3*w;
      }
    }
  }
  __syncthreads();

  // ---- per-i: stage S_T + rbf, MFMA ga/da, epilogue X, final bias MFMA ----
  #pragma unroll
  for (int ii=0; ii<4; ii++){
    { // S_T(i) write (bf16)
      int c=t>>1, l0=(t&1)*8;
      *(uint4*)&ST[c*40+l0] = make_uint4(
        packbf(S4i[ii][0],S4i[ii][1]), packbf(S4i[ii][2],S4i[ii][3]),
        packbf(S4i[ii][4],S4i[ii][5]), packbf(S4i[ii][6],S4i[ii][7]));
    }
    { // windowed rbf fill
      int jr=t>>3, sl=t&7;
      float d = dsm[ii][jr];
      int r0 = r0_of(d);
      #pragma unroll
      for (int u=0;u<9;u++){
        int r = sl*9+u;
        float val=0.f;
        if (r>=r0 && r<r0+16){ float dd=(d-(float)r*RBF_STEP)*RBF_INVSIG; val=__expf(-dd*dd); }
        rbfb[jr*72+r]=f2bf(val);
      }
    }
    __syncthreads();

    f32x4 zero4 = {0.f,0.f,0.f,0.f};
    f32x4 ga[2][2], da[2][2];
    #pragma unroll
    for(int a=0;a<2;a++){
      #pragma unroll
      for(int b2=0;b2<2;b2++){ ga[a][b2]=zero4; da[a][b2]=zero4; }
    }
    {
      bf16x8 bE[2];
      #pragma unroll
      for(int nt=0;nt<2;nt++) bE[nt] = *(const bf16x8*)&e2b[(nt*16+l15)*40 + q*8];
      #pragma unroll
      for(int mt=0;mt<2;mt++){
        bf16x8 aS = *(const bf16x8*)&ST[(wave*32+mt*16+l15)*40 + q*8];
        #pragma unroll
        for(int nt=0;nt<2;nt++)
          ga[mt][nt] = __builtin_amdgcn_mfma_f32_16x16x32_bf16(aS, bE[nt], ga[mt][nt], 0,0,0);
      }
      #pragma unroll
      for(int ks=0;ks<2;ks++){
        bf16x8 bR[2];
        #pragma unroll
        for(int nt=0;nt<2;nt++) bR[nt] = *(const bf16x8*)&rbfb[(nt*16+l15)*72 + ks*32 + q*8];
        #pragma unroll
        for(int mt=0;mt<2;mt++){
          bf16x8 aW = *(const bf16x8*)&wdT[(wave*32+mt*16+l15)*72 + ks*32 + q*8];
          #pragma unroll
          for(int nt=0;nt<2;nt++)
            da[mt][nt] = __builtin_amdgcn_mfma_f32_16x16x32_bf16(aW, bR[nt], da[mt][nt], 0,0,0);
        }
      }
    }
    #pragma unroll
    for(int mt=0;mt<2;mt++){
      int c0 = wave*32 + mt*16 + q*4;
      float4 bgv = *(const float4*)&bgs[c0];
      float4 bdv = *(const float4*)&bds[c0];
      #pragma unroll
      for(int nt=0;nt<2;nt++){
        float x0 = sigm(ga[mt][nt][0]+bgv.x)*(da[mt][nt][0]+bdv.x);
        float x1 = sigm(ga[mt][nt][1]+bgv.y)*(da[mt][nt][1]+bdv.y);
        float x2 = sigm(ga[mt][nt][2]+bgv.z)*(da[mt][nt][2]+bdv.z);
        float x3 = sigm(ga[mt][nt][3]+bgv.w)*(da[mt][nt][3]+bdv.w);
        *(uint2*)&Xb[(nt*16+l15)*136 + c0] = make_uint2(packbf(x0,x1), packbf(x2,x3));
      }
    }
    __syncthreads();

    if (wave < 2){
      f32x4 bacc = {0.f,0.f,0.f,0.f};
      #pragma unroll
      for(int ks=0;ks<4;ks++){
        bf16x8 aT = *(const bf16x8*)&wtT[l15*136 + ks*32 + q*8];
        bf16x8 bX = *(const bf16x8*)&Xb[(wave*16+l15)*136 + ks*32 + q*8];
        bacc = __builtin_amdgcn_mfma_f32_16x16x32_bf16(aT,bX,bacc,0,0,0);
      }
      if (q==0){   // rows h=0..3 in quad-0 regs; layout [n][h][i][j]
        int j = wave*16 + l15;
        float* base = biasw + (((size_t)n*4)*32 + (i0+ii))*32 + j;
        base[0] = bacc[0]; base[1024] = bacc[1]; base[2048] = bacc[2]; base[3072] = bacc[3];
      }
    }
  }
}

// ---------- K3: per-node QKV+og (MFMA) + attention + out-proj (MFMA) ----------
// LDS 48 KB: P segs q/k/v/og (4x8 KB, swizzled rows) + per-wave W tile slots (4x4 KB)
// wave w <-> segment w (q,k,v,og). No barriers in phase2 (all LDS wave-private).
__global__ __launch_bounds__(256,3) void k3_attn(
    const unsigned short* __restrict__ zw, const float* __restrict__ biasw,
    const unsigned short* __restrict__ wqkvogT, const unsigned short* __restrict__ woutT,
    const float* __restrict__ bq, const float* __restrict__ bkv, const float* __restrict__ bog,
    const float* __restrict__ bout, float* __restrict__ out)
{
  int n = blockIdx.x, t = threadIdx.x;
  int w = t>>6, lane = t&63, q = lane>>4, l15 = lane&15;
  int i3 = lane>>1, jh = lane&1;

  __shared__ __align__(16) char smem[49152];
  uint4* wdst = (uint4*)(smem + 32768);
  unsigned short* wtS = (unsigned short*)(smem + 32768);
  f32x4 zero4 = {0.f,0.f,0.f,0.f};

  // resident z B-frags (global, bypass LDS)
  bf16x8 zfr[2][4];
  #pragma unroll
  for (int nt=0;nt<2;nt++){
    const unsigned short* zr = zw + ((size_t)n*32 + nt*16 + l15)*128;
    #pragma unroll
    for (int ks=0;ks<4;ks++) zfr[nt][ks] = *(const bf16x8*)(zr + ks*32 + q*8);
  }
  // attention bias -> regs (coalesced, [n][h][i][j] layout)
  f32x4 br4[4];
  {
    const f32x4* bsrc = (const f32x4*)(biasw + (((size_t)n*4 + w)*32 + i3)*32 + jh*16);
    #pragma unroll
    for (int u=0;u<4;u++) br4[u] = bsrc[u];
  }
  const float* bseg = (w==0)? bq : (w==1)? bkv : (w==2)? (bkv+128) : bog;

  // ---- phase2: [32,128] @ [128,512] via MFMA, per-wave streamed W tiles ----
  const uint4* wsrc = (const uint4*)wqkvogT;
  int sb = w*2048, db = w*256;
  uint4 sreg[4];
  #pragma unroll
  for (int u=0;u<4;u++) sreg[u] = wsrc[sb + u*64 + lane];
  const unsigned short* arow = wtS + w*2048 + l15*128;
  for (int r=0;r<8;r++){
    #pragma unroll
    for (int u=0;u<4;u++) wdst[db + u*64 + lane] = sreg[u];
    if (r<7){
      #pragma unroll
      for (int u=0;u<4;u++) sreg[u] = wsrc[sb + (r+1)*256 + u*64 + lane];
    }
    float4 bv = *(const float4*)(bseg + r*16 + q*4);
    f32x4 acc0 = zero4, acc1 = zero4;
    int cg = w*128 + r*16 + l15;
    #pragma unroll
    for (int ks=0;ks<4;ks++){
      bf16x8 af = *(const bf16x8*)(arow + (((ks*4+q) + cg)&15)*8);
      acc0 = __builtin_amdgcn_mfma_f32_16x16x32_bf16(af, zfr[0][ks], acc0, 0,0,0);
      acc1 = __builtin_amdgcn_mfma_f32_16x16x32_bf16(af, zfr[1][ks], acc1, 0,0,0);
    }
    #pragma unroll
    for (int nt=0;nt<2;nt++){
      f32x4 a = nt? acc1 : acc0;
      float v0,v1,v2,v3;
      if (w==3){ v0=sigm(a[0]+bv.x); v1=sigm(a[1]+bv.y); v2=sigm(a[2]+bv.z); v3=sigm(a[3]+bv.w); }
      else     { v0=a[0]+bv.x; v1=a[1]+bv.y; v2=a[2]+bv.z; v3=a[3]+bv.w; }
      int i = nt*16 + l15;
      int blk = ((r*2 + (q>>1)) + i) & 15;
      *(uint2*)(smem + w*8192 + i*256 + blk*16 + (q&1)*8) = make_uint2(packbf(v0,v1), packbf(v2,v3));
    }
  }
  __syncthreads();

  // ---- phase3: attention (wave = head w; lane -> (i3, j-half)) ----
  float sc[16];
  {
    float qreg[32];
    #pragma unroll
    for (int dq=0;dq<4;dq++){
      uint4 qa = *(const uint4*)(smem + i3*256 + (((w*4+dq) + i3)&15)*16);
      unsigned int qu[4] = {qa.x,qa.y,qa.z,qa.w};
      #pragma unroll
      for (int u2=0;u2<4;u2++){ qreg[dq*8+2*u2]=bfl(qu[u2]); qreg[dq*8+2*u2+1]=bfh(qu[u2]); }
    }
    int j0 = jh*16;
    #pragma unroll
    for (int jj=0;jj<16;jj++){
      int j = j0+jj;
      float s = 0.f;
      #pragma unroll
      for (int dq=0;dq<4;dq++){
        uint4 ka = *(const uint4*)(smem + 8192 + j*256 + (((w*4+dq) + j)&15)*16);
        unsigned int ku[4] = {ka.x,ka.y,ka.z,ka.w};
        #pragma unroll
        for (int u2=0;u2<4;u2++)
          s += qreg[dq*8+2*u2]*bfl(ku[u2]) + qreg[dq*8+2*u2+1]*bfh(ku[u2]);
      }
      sc[jj] = s*0.17677669529663687f + br4[jj>>2][jj&3];
    }
  }
  {
    float mx = sc[0];
    #pragma unroll
    for (int jj=1;jj<16;jj++) mx = fmaxf(mx, sc[jj]);
    mx = fmaxf(mx, __shfl_xor(mx,1));
    float sum = 0.f;
    #pragma unroll
    for (int jj=0;jj<16;jj++){ sc[jj] = __expf(sc[jj]-mx); sum += sc[jj]; }
    sum += __shfl_xor(sum,1);
    float inv = 1.0f/sum;
    #pragma unroll
    for (int jj=0;jj<16;jj++) sc[jj] *= inv;
  }
  __syncthreads();              // all waves done reading q before y overwrites it
  {
    int dbase = w*32 + jh*16;
    int db8 = dbase >> 3;
    float o16[16];
    #pragma unroll
    for (int u=0;u<16;u++) o16[u]=0.f;
    #pragma unroll
    for (int j=0;j<32;j++){
      float pj = __shfl(sc[j & 15], (lane & 62) | (j >> 4));
      uint4 va0 = *(const uint4*)(smem + 16384 + j*256 + (((db8+0) + j)&15)*16);
      uint4 va1 = *(const uint4*)(smem + 16384 + j*256 + (((db8+1) + j)&15)*16);
      unsigned int vu[8] = {va0.x,va0.y,va0.z,va0.w,va1.x,va1.y,va1.z,va1.w};
      #pragma unroll
      for (int u2=0;u2<8;u2++){ o16[2*u2] += pj*bfl(vu[u2]); o16[2*u2+1] += pj*bfh(vu[u2]); }
    }
    uint4 ga0 = *(const uint4*)(smem + 24576 + i3*256 + (((db8+0) + i3)&15)*16);
    uint4 ga1 = *(const uint4*)(smem + 24576 + i3*256 + (((db8+1) + i3)&15)*16);
    unsigned int gu[8] = {ga0.x,ga0.y,ga0.z,ga0.w,ga1.x,ga1.y,ga1.z,ga1.w};
    #pragma unroll
    for (int u2=0;u2<8;u2++){
      float y0 = o16[2*u2]  *bfl(gu[u2]);
      float y1 = o16[2*u2+1]*bfh(gu[u2]);
      int c = dbase + 2*u2;
      *(unsigned int*)(smem + i3*256 + (((c>>3) + i3)&15)*16 + (c&7)*2) = packbf(y0,y1);
    }
  }
  __syncthreads();

  // ---- phase4: out = y @ w_out + b_out via MFMA ----
  bf16x8 yfr[2][4];
  #pragma unroll
  for (int mt=0;mt<2;mt++){
    int row = mt*16 + l15;
    #pragma unroll
    for (int ks=0;ks<4;ks++)
      yfr[mt][ks] = *(const bf16x8*)(smem + row*256 + (((ks*4+q) + row)&15)*16);
  }
  const uint4* osrc = (const uint4*)woutT;
  #pragma unroll
  for (int r2=0;r2<2;r2++){
    int c0 = (r2*4 + w)*16;
    #pragma unroll
    for (int u=0;u<4;u++) wdst[db + u*64 + lane] = osrc[c0*16 + u*64 + lane];
    int cg2 = c0 + l15;
    const unsigned short* brow = wtS + w*2048 + l15*128;
    f32x4 oa0 = zero4, oa1 = zero4;
    #pragma unroll
    for (int ks=0;ks<4;ks++){
      bf16x8 bf = *(const bf16x8*)(brow + (((ks*4+q) + cg2)&15)*8);
      oa0 = __builtin_amdgcn_mfma_f32_16x16x32_bf16(yfr[0][ks], bf, oa0, 0,0,0);
      oa1 = __builtin_amdgcn_mfma_f32_16x16x32_bf16(yfr[1][ks], bf, oa1, 0,0,0);
    }
    float bov = bout[cg2];
    #pragma unroll
    for (int mt=0;mt<2;mt++){
      f32x4 oa = mt? oa1 : oa0;
      #pragma unroll
      for (int rg=0; rg<4; rg++){
        int i = mt*16 + q*4 + rg;
        out[((size_t)n*32 + i)*128 + cg2] = oa[rg] + bov;
      }
    }
  }
}

// ---------- launch ----------
extern "C" void kernel_launch(void* const* d_in, const int* in_sizes, int n_in,
                              void* d_out, int out_size, void* d_ws, size_t ws_size,
                              hipStream_t stream)
{
  const float* nf  = (const float*)d_in[0];
  const float* tr  = (const float*)d_in[1];
  const float* ef  = (const float*)d_in[2];
  const long long* ei = (const long long*)d_in[3];
  const float* wl  = (const float*)d_in[4];  const float* bl  = (const float*)d_in[5];
  const float* wr  = (const float*)d_in[6];  const float* br  = (const float*)d_in[7];
  const float* wbg = (const float*)d_in[8];  const float* bbg = (const float*)d_in[9];
  const float* wdi = (const float*)d_in[10]; const float* bdi = (const float*)d_in[11];
  const float* wtb = (const float*)d_in[12];
  const float* lng = (const float*)d_in[13]; const float* lnb = (const float*)d_in[14];
  const float* wq  = (const float*)d_in[15]; const float* bq  = (const float*)d_in[16];
  const float* wkv = (const float*)d_in[17]; const float* bkv = (const float*)d_in[18];
  const float* wo  = (const float*)d_in[19]; const float* bo  = (const float*)d_in[20];
  const float* wog = (const float*)d_in[21]; const float* bog = (const float*)d_in[22];
  float* outp = (float*)d_out;
  float* ws = (float*)d_ws;
  // ws layout (floats). zw is E*CZ bf16 = 3,145,728 shorts = 1,572,864 floats.
  float* nlw = ws;                                            // [0, 12288)
  float* nrw = ws + 12288;                                    // [12288, 24576)
  float* biasw = ws + 24576;                                  // [24576, 3170304)  [n][h][i][j]
  unsigned short* zw      = (unsigned short*)(ws + 3170304);  // [3170304, 4743168)
  unsigned short* wqkvogT = (unsigned short*)(ws + 4743168);  // 32768 floats
  unsigned short* woutT   = (unsigned short*)(ws + 4775936);  // 8192 floats
  unsigned short* wdTg    = (unsigned short*)(ws + 4784128);  // 4608 floats
  unsigned short* wtTg    = (unsigned short*)(ws + 4788736);  // 1088 floats -> end 4789824

  hipLaunchKernelGGL(k0_prep, dim3(45), dim3(256), 0, stream,
                     wq, wkv, wog, wo, wdi, wtb, wqkvogT, woutT, wdTg, wtTg);
  hipLaunchKernelGGL(k1_pre, dim3(1632), dim3(256), 0, stream,
                     nf, ef, wl, bl, wr, br, lng, lnb, nlw, nrw, zw);
  hipLaunchKernelGGL(k2_bias, dim3(6144), dim3(256), 0, stream,
                     ei, tr, nlw, nrw, wbg, bbg, wdTg, bdi, wtTg, biasw);
  hipLaunchKernelGGL(k3_attn, dim3(768), dim3(256), 0, stream,
                     zw, biasw, wqkvogT, woutT, bq, bkv, bog, bo, outp);
}